// Round 20
// baseline (177.137 us; speedup 1.0000x reference)
//
#include <hip/hip_runtime.h>
#include <hip/hip_bf16.h>

// Problem constants (LegacyScan2DOperator): B=8, H=96, W=96, D=192, C=384.
#define NB 8
#define NH 96
#define NW 96
#define ND 192
#define NC 384
#define NPOS (NB*NH*NW)            // 73728 spatial positions
// padded w-record stride for loc_t/acc_t: 96*384 + 128 ushorts = 73984 B
// (= 289 x 256B lines; 289 coprime with 128 -> records sweep all HBM channels;
//  the unpadded 73728 B = 288 lines advanced the channel by 32 each record,
//  concentrating each block's traffic on ~1/10 of the channels)
#define WSTRIDE (NH*NC + 128)

#define DECAY 0.6f
#define GAIN 0.4f
#define D12 2.1767823e-3f          // 0.6^12
#define D16 2.8211099e-4f          // 0.6^16
#define D24 4.7383813e-6f          // 0.6^24

typedef __attribute__((ext_vector_type(8))) short bf16x8;
typedef __attribute__((ext_vector_type(4))) float f32x4;
typedef __attribute__((ext_vector_type(4))) unsigned short us4;

__device__ inline unsigned short f2bf(float f) {
  unsigned u = __float_as_uint(f);
  u += 0x7fff + ((u >> 16) & 1);          // RNE
  return (unsigned short)(u >> 16);
}
__device__ inline float bf2f(unsigned short u) {
  return __uint_as_float((unsigned)u << 16);
}

__device__ inline void gload16(const void* g, void* l) {
  __builtin_amdgcn_global_load_lds(
      (const __attribute__((address_space(1))) void*)g,
      (__attribute__((address_space(3))) void*)l, 16, 0, 0);
}

__device__ inline f32x4 ldf4(const float* p) {
  return *reinterpret_cast<const f32x4*>(p);
}
__device__ inline f32x4 ldb4(const unsigned short* p) {
  us4 v = *reinterpret_cast<const us4*>(p);
  return (f32x4){bf2f(v.x), bf2f(v.y), bf2f(v.z), bf2f(v.w)};
}
__device__ inline void stb4(unsigned short* p, f32x4 v) {
  us4 o = {f2bf(v[0]), f2bf(v[1]), f2bf(v[2]), f2bf(v[3])};
  *reinterpret_cast<us4*>(p) = o;
}
// packed bf16x4 (uint2) <-> f32x4
__device__ inline uint2 pk4(f32x4 v) {
  us4 o = {f2bf(v[0]), f2bf(v[1]), f2bf(v[2]), f2bf(v[3])};
  uint2 r; __builtin_memcpy(&r, &o, 8); return r;
}
__device__ inline f32x4 up4(uint2 p) {
  return (f32x4){__uint_as_float(p.x << 16), __uint_as_float(p.x & 0xffff0000u),
                 __uint_as_float(p.y << 16), __uint_as_float(p.y & 0xffff0000u)};
}
// pack 8 f32 -> bf16x8
__device__ inline bf16x8 pk8(f32x4 a, f32x4 b) {
  bf16x8 r;
#pragma unroll
  for (int i = 0; i < 4; ++i) {
    r[i]     = (short)f2bf(a[i]);
    r[i + 4] = (short)f2bf(b[i]);
  }
  return r;
}
// swizzled byte offset inside the mix tile: row-major 768B rows, XOR bank fix
__device__ inline unsigned mswz(int row, int byteInRow) {
  return (unsigned)(row * 768 + (byteInRow ^ ((row & 7) << 4)));
}

// ------------- combined weight conversions (one launch) ---------------------
__global__ __launch_bounds__(256) void cvt_w_kernel(
    const float* __restrict__ Wi, const float* __restrict__ Wo,
    unsigned short* __restrict__ WtI, unsigned short* __restrict__ WtO) {
  int idx = blockIdx.x * 256 + threadIdx.x;
  if (idx < ND * NC) {
    int k = idx / NC, c = idx % NC;
    WtI[c * ND + k] = f2bf(Wi[idx]);
  } else {
    int j = idx - ND * NC;
    int k = j / ND, d = j % ND;
    WtO[d * NC + k] = f2bf(Wo[j]);
  }
}

// ---------------- MFMA GEMM (in_proj): proj = x @ W_in + b ------------------
// A is f32 in global, staged raw via global_load_lds with granule-XOR swizzle.
template<int K, int N, int BN>
__global__ __launch_bounds__(256) void gemm_kernel(
    const float* __restrict__ A32,
    const unsigned short* __restrict__ Bt,
    const float* __restrict__ bias,
    unsigned short* __restrict__ C) {
  constexpr int NF = BN / 32;
  __shared__ __align__(16) unsigned short lsA[8192];
  __shared__ __align__(16) unsigned short lsB[4 * BN * 8];

  const int tid = threadIdx.x;
  const int lane = tid & 63;
  const int wid = tid >> 6;
  const int wm = wid >> 1, wn = wid & 1;
  const int kg = lane >> 4, r16 = lane & 15;
  const int m0 = blockIdx.x * 128;
  const int n0 = blockIdx.y * BN;

  const float* srcAf[4]; float* dstAf[4];
  {
    float* lsAf = (float*)lsA;
#pragma unroll
    for (int p = 0; p < 4; ++p) {
      int s = tid + p * 256;              // 1024 slots of 16B
      int row = s >> 3, g = s & 7;
      int gg = g ^ (row & 7);
      srcAf[p] = A32 + (size_t)(m0 + row) * K + gg * 4;
      dstAf[p] = lsAf + s * 4;
    }
  }
  const unsigned short* srcB0 = Bt + (size_t)(n0 + (tid & (BN - 1))) * K + (tid / BN) * 8;
  const int sb1 = tid + 256;
  const unsigned short* srcBh = Bt + (size_t)(n0 + (sb1 & 127)) * K + (sb1 >> 7) * 8;

  int boff[NF];
#pragma unroll
  for (int n = 0; n < NF; ++n)
    boff[n] = (kg * BN + wn * (BN / 2) + n * 16 + r16) * 8;

  f32x4 acc[4][NF];
  float bv[NF];
#pragma unroll
  for (int n = 0; n < NF; ++n) bv[n] = bias[n0 + wn * (BN / 2) + n * 16 + r16];
#pragma unroll
  for (int m = 0; m < 4; ++m)
#pragma unroll
    for (int n = 0; n < NF; ++n)
      acc[m][n] = (f32x4){bv[n], bv[n], bv[n], bv[n]};

  for (int ks = 0; ks < K / 32; ++ks) {
    const int ke = ks * 32;
#pragma unroll
    for (int p = 0; p < 4; ++p) gload16(srcAf[p] + ke, dstAf[p]);
    gload16(srcB0 + ke, &lsB[tid * 8]);
    if constexpr (BN == 128) gload16(srcBh + ke, &lsB[(tid + 256) * 8]);
    __syncthreads();
    bf16x8 af[4], bfr[NF];
    {
      const float* lsAf = (const float*)lsA;
      const int r7 = r16 & 7;
#pragma unroll
      for (int m = 0; m < 4; ++m) {
        const int rowf = wm * 64 + m * 16 + r16;
        const float* rp = lsAf + rowf * 32;
        f32x4 a0 = *reinterpret_cast<const f32x4*>(rp + ((2 * kg) ^ r7) * 4);
        f32x4 a1 = *reinterpret_cast<const f32x4*>(rp + ((2 * kg + 1) ^ r7) * 4);
        af[m] = pk8(a0, a1);
      }
    }
#pragma unroll
    for (int n = 0; n < NF; ++n)
      bfr[n] = *reinterpret_cast<const bf16x8*>(&lsB[boff[n]]);
#pragma unroll
    for (int m = 0; m < 4; ++m)
#pragma unroll
      for (int n = 0; n < NF; ++n)
        acc[m][n] = __builtin_amdgcn_mfma_f32_16x16x32_bf16(af[m], bfr[n], acc[m][n], 0, 0, 0);
    __syncthreads();
  }

#pragma unroll
  for (int m = 0; m < 4; ++m) {
    const int row = m0 + wm * 64 + m * 16 + kg * 4;
#pragma unroll
    for (int n = 0; n < NF; ++n) {
      const int col = n0 + wn * (BN / 2) + n * 16 + r16;
#pragma unroll
      for (int j = 0; j < 4; ++j)
        C[(size_t)(row + j) * N + col] = f2bf(acc[m][n][j]);
    }
  }
}

// -- fused depthwise 3x3 conv + horizontal scans (aggregate exchange) --------
// block -> (b,h) via XCD-chunked map: all h of one batch image on one XCD,
// so the bh-1/bh+1 proj rows are L2-resident. 576 thr = (c4, wseg of 16).
// Writes loc_t / acc_t (b,w,h,c) transposed with PADDED w-stride (WSTRIDE),
// SEPARATE buffers (interleaving regressed 2.5x — R11).
__global__ __launch_bounds__(576) void dh_kernel(
    const unsigned short* __restrict__ proj, const float* __restrict__ cw,
    unsigned short* __restrict__ loc_t, unsigned short* __restrict__ acc_t) {
  __shared__ f32x4 agf[6][96];
  __shared__ f32x4 agb[6][96];   // 18432 B
  const int tid = threadIdx.x;
  const int c4 = tid % 96;
  const int seg = tid / 96;      // wseg 0..5
  const int w0 = seg * 16;
  const int bid = blockIdx.x;
  const int bh = (bid & 7) * NH + (bid >> 3);   // XCD-chunked (768 = 8*96)
  const int h = bh % NH;
  const int b = bh / NH;

  f32x4 raw[9];
  const float* cwp = cw + (size_t)c4 * 36;
#pragma unroll
  for (int i = 0; i < 9; ++i) raw[i] = ldf4(cwp + i * 4);
  f32x4 qq[9];
#pragma unroll
  for (int tap = 0; tap < 9; ++tap)
#pragma unroll
    for (int c = 0; c < 4; ++c)
      qq[tap][c] = raw[(c * 9 + tap) >> 2][(c * 9 + tap) & 3];

  const bool hm = (h > 0), hp = (h < NH - 1);
  const unsigned short* rowm = proj + ((size_t)(bh - 1) * NW) * NC + c4 * 4;
  const unsigned short* rowc = proj + ((size_t)bh * NW) * NC + c4 * 4;
  const unsigned short* rowp = proj + ((size_t)(bh + 1) * NW) * NC + c4 * 4;
  unsigned short* tbase = loc_t + (size_t)(b * NW + w0) * WSTRIDE + (size_t)h * NC + c4 * 4;
  unsigned short* abase = acc_t + (size_t)(b * NW + w0) * WSTRIDE + (size_t)h * NC + c4 * 4;
  const size_t wst = (size_t)WSTRIDE;

  const f32x4 z = {0.f, 0.f, 0.f, 0.f};
  f32x4 colL[3], colC[3], colR[3];
  if (w0 > 0) {
    colL[0] = hm ? ldb4(rowm + (size_t)(w0 - 1) * NC) : z;
    colL[1] = ldb4(rowc + (size_t)(w0 - 1) * NC);
    colL[2] = hp ? ldb4(rowp + (size_t)(w0 - 1) * NC) : z;
  } else { colL[0] = z; colL[1] = z; colL[2] = z; }
  colC[0] = hm ? ldb4(rowm + (size_t)w0 * NC) : z;
  colC[1] = ldb4(rowc + (size_t)w0 * NC);
  colC[2] = hp ? ldb4(rowp + (size_t)w0 * NC) : z;

  uint2 xr[16];
#pragma unroll
  for (int i = 0; i < 16; ++i) {
    const int w = w0 + i;
    if (w + 1 < NW) {
      colR[0] = hm ? ldb4(rowm + (size_t)(w + 1) * NC) : z;
      colR[1] = ldb4(rowc + (size_t)(w + 1) * NC);
      colR[2] = hp ? ldb4(rowp + (size_t)(w + 1) * NC) : z;
    } else { colR[0] = z; colR[1] = z; colR[2] = z; }
    f32x4 a = colL[0] * qq[0] + colC[0] * qq[1] + colR[0] * qq[2]
            + colL[1] * qq[3] + colC[1] * qq[4] + colR[1] * qq[5]
            + colL[2] * qq[6] + colC[2] * qq[7] + colR[2] * qq[8];
    xr[i] = pk4(a);
    *reinterpret_cast<uint2*>(tbase + (size_t)i * wst) = xr[i];
    colL[0] = colC[0]; colL[1] = colC[1]; colL[2] = colC[2];
    colC[0] = colR[0]; colC[1] = colR[1]; colC[2] = colR[2];
  }

  f32x4 Af = z, Ab = z;
#pragma unroll
  for (int i = 0; i < 16; ++i) Af = DECAY * Af + GAIN * up4(xr[i]);
#pragma unroll
  for (int i = 15; i >= 0; --i) Ab = DECAY * Ab + GAIN * up4(xr[i]);
  agf[seg][c4] = Af; agb[seg][c4] = Ab;
  __syncthreads();
  f32x4 Fin = z, Bin = z;
  if (seg >= 1) Fin = agf[seg - 1][c4];
  if (seg >= 2) Fin += D16 * agf[seg - 2][c4];
  if (seg <= 4) Bin = agb[seg + 1][c4];
  if (seg <= 3) Bin += D16 * agb[seg + 2][c4];

  uint2 bwp[16];
  f32x4 Bs = Bin;
#pragma unroll
  for (int i = 15; i >= 0; --i) {
    Bs = DECAY * Bs + GAIN * up4(xr[i]);
    bwp[i] = pk4(Bs);
  }
  f32x4 Fs = Fin;
#pragma unroll
  for (int i = 0; i < 16; ++i) {
    Fs = DECAY * Fs + GAIN * up4(xr[i]);
    stb4(abase + (size_t)i * wst, Fs + up4(bwp[i]));
  }
}

// -- MEGA-FUSED: vertical scans + mix + layernorm + out_proj GEMM ------------
// block = (b,w), 768 threads = 12 waves, 1 block/CU (mix tile 73.7 KB).
// Scan: R12's exact form (VGPR 72/76, no spill). GEMM: BK=64 double-buffered.
__global__ __launch_bounds__(768) void vgemm_kernel(
    const unsigned short* __restrict__ loc_t, const unsigned short* __restrict__ acc_t,
    const float* __restrict__ g, const float* __restrict__ bb,
    const unsigned short* __restrict__ WtO, const float* __restrict__ bo,
    float* __restrict__ out) {
  __shared__ __align__(16) unsigned short mix[96 * NC];   // 73728 B
  __shared__ __align__(16) unsigned short lsB[2][12288];  // 2 x 24576 B
  f32x4* ag = (f32x4*)mix;            // [2][8][96] multiplexed head (24.6 KB)
  char* mixc = (char*)mix;
  const int tid = threadIdx.x;
  const int lane = tid & 63;
  const int kg = lane >> 4, r16 = lane & 15;
  const int c4 = tid % 96;
  const int seg = tid / 96;                               // hseg 0..7
  const int h0 = seg * 12;
  const int bw = blockIdx.x;                              // b*NW + w

  // ---- prefetch B chunk 0 (64 k) async; drained by the phase-1 barrier ----
  {
    int d = tid % 192, kgg = tid / 192;                   // kgg 0..3
    gload16(WtO + (size_t)d * NC + kgg * 8, &lsB[0][tid * 8]);
    int s2 = tid + 768, d2 = s2 % 192, kg2 = s2 / 192;    // kg2 4..7
    gload16(WtO + (size_t)d2 * NC + kg2 * 8, &lsB[0][s2 * 8]);
  }

  // ---- phase 1: vertical scans (aggregate exchange, 12-row segments) ----
  const size_t base = (size_t)bw * WSTRIDE + (size_t)h0 * NC + c4 * 4;
  const unsigned short* lp = loc_t + base;
  const unsigned short* ap = acc_t + base;
  uint2 xr[12], avp[12];
#pragma unroll
  for (int i = 0; i < 12; ++i) xr[i] = *reinterpret_cast<const uint2*>(lp + (size_t)i * NC);
#pragma unroll
  for (int i = 0; i < 12; ++i) avp[i] = *reinterpret_cast<const uint2*>(ap + (size_t)i * NC);

  const f32x4 z = {0.f, 0.f, 0.f, 0.f};
  f32x4 Af = z, Ab = z;
#pragma unroll
  for (int i = 0; i < 12; ++i) Af = DECAY * Af + GAIN * up4(xr[i]);
#pragma unroll
  for (int i = 11; i >= 0; --i) Ab = DECAY * Ab + GAIN * up4(xr[i]);
  ag[seg * 96 + c4] = Af;
  ag[768 + seg * 96 + c4] = Ab;
  __syncthreads();
  f32x4 Fin = z, Bin = z;
  if (seg >= 1) Fin = ag[(seg - 1) * 96 + c4];
  if (seg >= 2) Fin += D12 * ag[(seg - 2) * 96 + c4];
  if (seg >= 3) Fin += D24 * ag[(seg - 3) * 96 + c4];
  if (seg <= 6) Bin = ag[768 + (seg + 1) * 96 + c4];
  if (seg <= 5) Bin += D12 * ag[768 + (seg + 2) * 96 + c4];
  if (seg <= 4) Bin += D24 * ag[768 + (seg + 3) * 96 + c4];
  __syncthreads();                       // aggregate area free; mix writable

  // bwd pass: partial = x + 0.25*(acc + bt) -> swizzled mix tile
  f32x4 Bs = Bin;
#pragma unroll
  for (int i = 11; i >= 0; --i) {
    f32x4 xv = up4(xr[i]);
    Bs = DECAY * Bs + GAIN * xv;
    f32x4 part = xv + 0.25f * (up4(avp[i]) + Bs);
    stb4((unsigned short*)(mixc + mswz(h0 + i, c4 * 8)), part);
  }
  // fwd pass: final = partial + 0.25*tb (own slots)
  f32x4 Fs = Fin;
#pragma unroll
  for (int i = 0; i < 12; ++i) {
    Fs = DECAY * Fs + GAIN * up4(xr[i]);
    unsigned short* slot = (unsigned short*)(mixc + mswz(h0 + i, c4 * 8));
    stb4(slot, ldb4(slot) + 0.25f * Fs);
  }
  __syncthreads();

  // ---- phase 2: layernorm in-place in LDS (12 waves, wave-per-row) ----
  const int wave = tid >> 6;
  const int cb = lane * 6;
  {
    float gv[6], bv6[6];
#pragma unroll
    for (int i = 0; i < 6; ++i) { gv[i] = g[cb + i]; bv6[i] = bb[cb + i]; }
    for (int h = wave; h < NH; h += 12) {
      ushort2* p0 = (ushort2*)(mixc + mswz(h, lane * 12));
      ushort2* p1 = (ushort2*)(mixc + mswz(h, lane * 12 + 4));
      ushort2* p2 = (ushort2*)(mixc + mswz(h, lane * 12 + 8));
      ushort2 a2 = *p0, b2 = *p1, c2 = *p2;
      float v[6];
      v[0] = bf2f(a2.x); v[1] = bf2f(a2.y);
      v[2] = bf2f(b2.x); v[3] = bf2f(b2.y);
      v[4] = bf2f(c2.x); v[5] = bf2f(c2.y);
      float sm = 0.f, s2 = 0.f;
#pragma unroll
      for (int i = 0; i < 6; ++i) { sm += v[i]; s2 += v[i] * v[i]; }
#pragma unroll
      for (int o = 32; o > 0; o >>= 1) {
        sm += __shfl_xor(sm, o, 64);
        s2 += __shfl_xor(s2, o, 64);
      }
      float mu = sm * (1.f / NC);
      float r = rsqrtf(s2 * (1.f / NC) - mu * mu + 1e-5f);
      unsigned short o6[6];
#pragma unroll
      for (int i = 0; i < 6; ++i)
        o6[i] = f2bf((v[i] - mu) * r * gv[i] + bv6[i]);
      *p0 = (ushort2){o6[0], o6[1]};
      *p1 = (ushort2){o6[2], o6[3]};
      *p2 = (ushort2){o6[4], o6[5]};
    }
  }
  __syncthreads();

  // ---- phase 3: GEMM  out[96 x 192] = mix[96 x 384] @ WtO^T + b_out ----
  // BK=64 double-buffered: 6 chunks, 12 MFMA/wave between barriers.
  const int wm = wave >> 2, wn = wave & 3;     // 3x4 waves, 32x48 tiles
  f32x4 acc[2][3];
  {
    float bv[3];
#pragma unroll
    for (int n = 0; n < 3; ++n) bv[n] = bo[wn * 48 + n * 16 + r16];
#pragma unroll
    for (int m = 0; m < 2; ++m)
#pragma unroll
      for (int n = 0; n < 3; ++n)
        acc[m][n] = (f32x4){bv[n], bv[n], bv[n], bv[n]};
  }
  for (int ck = 0; ck < 6; ++ck) {
    if (ck < 5) {
      unsigned short* dst = lsB[(ck + 1) & 1];
      int d = tid % 192, kgg = tid / 192;
      gload16(WtO + (size_t)d * NC + (ck + 1) * 64 + kgg * 8, &dst[tid * 8]);
      int s2 = tid + 768, d2 = s2 % 192, kg2 = s2 / 192;
      gload16(WtO + (size_t)d2 * NC + (ck + 1) * 64 + kg2 * 8, &dst[s2 * 8]);
    }
    const unsigned short* bufp = lsB[ck & 1];
#pragma unroll
    for (int hh = 0; hh < 2; ++hh) {
      bf16x8 af[2], bfr[3];
#pragma unroll
      for (int m = 0; m < 2; ++m) {
        const int row = wm * 32 + m * 16 + r16;
        af[m] = *reinterpret_cast<const bf16x8*>(
            mixc + mswz(row, ck * 128 + hh * 64 + kg * 16));
      }
#pragma unroll
      for (int n = 0; n < 3; ++n)
        bfr[n] = *reinterpret_cast<const bf16x8*>(
            &bufp[((hh * 4 + kg) * 192 + wn * 48 + n * 16 + r16) * 8]);
#pragma unroll
      for (int m = 0; m < 2; ++m)
#pragma unroll
        for (int n = 0; n < 3; ++n)
          acc[m][n] = __builtin_amdgcn_mfma_f32_16x16x32_bf16(af[m], bfr[n], acc[m][n], 0, 0, 0);
    }
    __syncthreads();
  }

  // C write: rows are h of this (b,w) column -> out[(b,h,w)][d], f32
  const int bq = bw / NW, wq = bw % NW;
#pragma unroll
  for (int m = 0; m < 2; ++m) {
    const int hbase = wm * 32 + m * 16 + kg * 4;
#pragma unroll
    for (int n = 0; n < 3; ++n) {
      const int d = wn * 48 + n * 16 + r16;
#pragma unroll
      for (int j = 0; j < 4; ++j)
        out[((size_t)(bq * NH + hbase + j) * NW + wq) * ND + d] = acc[m][n][j];
    }
  }
}

extern "C" void kernel_launch(void* const* d_in, const int* in_sizes, int n_in,
                              void* d_out, int out_size, void* d_ws, size_t ws_size,
                              hipStream_t stream) {
  const float* x    = (const float*)d_in[0];
  const float* W_in = (const float*)d_in[1];
  const float* b_in = (const float*)d_in[2];
  const float* cw   = (const float*)d_in[3];
  const float* ln_g = (const float*)d_in[4];
  const float* ln_b = (const float*)d_in[5];
  const float* W_out= (const float*)d_in[6];
  const float* b_out= (const float*)d_in[7];
  float* out = (float*)d_out;

  // bf16 workspace layout (ushort element offsets); ~171 MB
  unsigned short* wsu   = (unsigned short*)d_ws;
  unsigned short* proj  = wsu;                          // 28,311,552 (b,h,w,c)
  unsigned short* loc_t = proj + 28311552;              // 768*WSTRIDE (padded)
  unsigned short* acc_t = loc_t + (size_t)NB * NW * WSTRIDE;
  unsigned short* WtI   = acc_t + (size_t)NB * NW * WSTRIDE;   // 73,728
  unsigned short* WtO   = WtI + 73728;                  // 73,728

  // 1) weight conversions (one launch)
  cvt_w_kernel<<<(2 * ND * NC) / 256, 256, 0, stream>>>(W_in, W_out, WtI, WtO);
  // 2) in_proj MFMA GEMM (reads f32 x directly) -> bf16 proj  [M,K=192,N=384]
  {
    dim3 g(NPOS / 128, NC / 128);
    gemm_kernel<ND, NC, 128><<<g, 256, 0, stream>>>(x, WtI, b_in, proj);
  }
  // 3) fused depthwise conv + horizontal scans -> loc_t, acc_t (transposed,
  //    XCD-chunked block map, padded w-stride)
  dh_kernel<<<NB * NH, 576, 0, stream>>>(proj, cw, loc_t, acc_t);
  // 4) mega-fused vertical scans + mix + LN + out_proj GEMM -> f32 out
  vgemm_kernel<<<NB * NW, 768, 0, stream>>>(loc_t, acc_t, ln_g, ln_b,
                                            WtO, b_out, out);
}

// Round 21
// 174.898 us; speedup vs baseline: 1.0128x; 1.0128x over previous
//
#include <hip/hip_runtime.h>
#include <hip/hip_bf16.h>

// Problem constants (LegacyScan2DOperator): B=8, H=96, W=96, D=192, C=384.
#define NB 8
#define NH 96
#define NW 96
#define ND 192
#define NC 384
#define NPOS (NB*NH*NW)            // 73728 spatial positions

#define DECAY 0.6f
#define GAIN 0.4f
#define D12 2.1767823e-3f          // 0.6^12
#define D16 2.8211099e-4f          // 0.6^16
#define D24 4.7383813e-6f          // 0.6^24

typedef __attribute__((ext_vector_type(8))) short bf16x8;
typedef __attribute__((ext_vector_type(4))) float f32x4;
typedef __attribute__((ext_vector_type(4))) unsigned short us4;

__device__ inline unsigned short f2bf(float f) {
  unsigned u = __float_as_uint(f);
  u += 0x7fff + ((u >> 16) & 1);          // RNE
  return (unsigned short)(u >> 16);
}
__device__ inline float bf2f(unsigned short u) {
  return __uint_as_float((unsigned)u << 16);
}

__device__ inline void gload16(const void* g, void* l) {
  __builtin_amdgcn_global_load_lds(
      (const __attribute__((address_space(1))) void*)g,
      (__attribute__((address_space(3))) void*)l, 16, 0, 0);
}

__device__ inline f32x4 ldf4(const float* p) {
  return *reinterpret_cast<const f32x4*>(p);
}
__device__ inline f32x4 ldb4(const unsigned short* p) {
  us4 v = *reinterpret_cast<const us4*>(p);
  return (f32x4){bf2f(v.x), bf2f(v.y), bf2f(v.z), bf2f(v.w)};
}
__device__ inline void stb4(unsigned short* p, f32x4 v) {
  us4 o = {f2bf(v[0]), f2bf(v[1]), f2bf(v[2]), f2bf(v[3])};
  *reinterpret_cast<us4*>(p) = o;
}
// packed bf16x4 (uint2) <-> f32x4
__device__ inline uint2 pk4(f32x4 v) {
  us4 o = {f2bf(v[0]), f2bf(v[1]), f2bf(v[2]), f2bf(v[3])};
  uint2 r; __builtin_memcpy(&r, &o, 8); return r;
}
__device__ inline f32x4 up4(uint2 p) {
  return (f32x4){__uint_as_float(p.x << 16), __uint_as_float(p.x & 0xffff0000u),
                 __uint_as_float(p.y << 16), __uint_as_float(p.y & 0xffff0000u)};
}
// pack 8 f32 -> bf16x8
__device__ inline bf16x8 pk8(f32x4 a, f32x4 b) {
  bf16x8 r;
#pragma unroll
  for (int i = 0; i < 4; ++i) {
    r[i]     = (short)f2bf(a[i]);
    r[i + 4] = (short)f2bf(b[i]);
  }
  return r;
}
// swizzled byte offset inside the mix tile: row-major 768B rows, XOR bank fix
__device__ inline unsigned mswz(int row, int byteInRow) {
  return (unsigned)(row * 768 + (byteInRow ^ ((row & 7) << 4)));
}

// ------------- combined weight conversions (one launch) ---------------------
__global__ __launch_bounds__(256) void cvt_w_kernel(
    const float* __restrict__ Wi, const float* __restrict__ Wo,
    unsigned short* __restrict__ WtI, unsigned short* __restrict__ WtO) {
  int idx = blockIdx.x * 256 + threadIdx.x;
  if (idx < ND * NC) {
    int k = idx / NC, c = idx % NC;
    WtI[c * ND + k] = f2bf(Wi[idx]);
  } else {
    int j = idx - ND * NC;
    int k = j / ND, d = j % ND;
    WtO[d * NC + k] = f2bf(Wo[j]);
  }
}

// ---------------- MFMA GEMM (in_proj): proj = x @ W_in + b ------------------
// A is f32 in global, staged raw via global_load_lds with granule-XOR swizzle.
template<int K, int N, int BN>
__global__ __launch_bounds__(256) void gemm_kernel(
    const float* __restrict__ A32,
    const unsigned short* __restrict__ Bt,
    const float* __restrict__ bias,
    unsigned short* __restrict__ C) {
  constexpr int NF = BN / 32;
  __shared__ __align__(16) unsigned short lsA[8192];
  __shared__ __align__(16) unsigned short lsB[4 * BN * 8];

  const int tid = threadIdx.x;
  const int lane = tid & 63;
  const int wid = tid >> 6;
  const int wm = wid >> 1, wn = wid & 1;
  const int kg = lane >> 4, r16 = lane & 15;
  const int m0 = blockIdx.x * 128;
  const int n0 = blockIdx.y * BN;

  const float* srcAf[4]; float* dstAf[4];
  {
    float* lsAf = (float*)lsA;
#pragma unroll
    for (int p = 0; p < 4; ++p) {
      int s = tid + p * 256;              // 1024 slots of 16B
      int row = s >> 3, g = s & 7;
      int gg = g ^ (row & 7);
      srcAf[p] = A32 + (size_t)(m0 + row) * K + gg * 4;
      dstAf[p] = lsAf + s * 4;
    }
  }
  const unsigned short* srcB0 = Bt + (size_t)(n0 + (tid & (BN - 1))) * K + (tid / BN) * 8;
  const int sb1 = tid + 256;
  const unsigned short* srcBh = Bt + (size_t)(n0 + (sb1 & 127)) * K + (sb1 >> 7) * 8;

  int boff[NF];
#pragma unroll
  for (int n = 0; n < NF; ++n)
    boff[n] = (kg * BN + wn * (BN / 2) + n * 16 + r16) * 8;

  f32x4 acc[4][NF];
  float bv[NF];
#pragma unroll
  for (int n = 0; n < NF; ++n) bv[n] = bias[n0 + wn * (BN / 2) + n * 16 + r16];
#pragma unroll
  for (int m = 0; m < 4; ++m)
#pragma unroll
    for (int n = 0; n < NF; ++n)
      acc[m][n] = (f32x4){bv[n], bv[n], bv[n], bv[n]};

  for (int ks = 0; ks < K / 32; ++ks) {
    const int ke = ks * 32;
#pragma unroll
    for (int p = 0; p < 4; ++p) gload16(srcAf[p] + ke, dstAf[p]);
    gload16(srcB0 + ke, &lsB[tid * 8]);
    if constexpr (BN == 128) gload16(srcBh + ke, &lsB[(tid + 256) * 8]);
    __syncthreads();
    bf16x8 af[4], bfr[NF];
    {
      const float* lsAf = (const float*)lsA;
      const int r7 = r16 & 7;
#pragma unroll
      for (int m = 0; m < 4; ++m) {
        const int rowf = wm * 64 + m * 16 + r16;
        const float* rp = lsAf + rowf * 32;
        f32x4 a0 = *reinterpret_cast<const f32x4*>(rp + ((2 * kg) ^ r7) * 4);
        f32x4 a1 = *reinterpret_cast<const f32x4*>(rp + ((2 * kg + 1) ^ r7) * 4);
        af[m] = pk8(a0, a1);
      }
    }
#pragma unroll
    for (int n = 0; n < NF; ++n)
      bfr[n] = *reinterpret_cast<const bf16x8*>(&lsB[boff[n]]);
#pragma unroll
    for (int m = 0; m < 4; ++m)
#pragma unroll
      for (int n = 0; n < NF; ++n)
        acc[m][n] = __builtin_amdgcn_mfma_f32_16x16x32_bf16(af[m], bfr[n], acc[m][n], 0, 0, 0);
    __syncthreads();
  }

#pragma unroll
  for (int m = 0; m < 4; ++m) {
    const int row = m0 + wm * 64 + m * 16 + kg * 4;
#pragma unroll
    for (int n = 0; n < NF; ++n) {
      const int col = n0 + wn * (BN / 2) + n * 16 + r16;
#pragma unroll
      for (int j = 0; j < 4; ++j)
        C[(size_t)(row + j) * N + col] = f2bf(acc[m][n][j]);
    }
  }
}

// -- fused depthwise 3x3 conv + horizontal scans (aggregate exchange) --------
// block -> (b,h) via XCD-chunked map: all h of one batch image on one XCD,
// so the bh-1/bh+1 proj rows are L2-resident. 576 thr = (c4, wseg of 16).
// Writes loc_t / acc_t (b,w,h,c) transposed, SEPARATE buffers (interleaving
// regressed 2.5x — R11; 256B stride padding was null — R19).
__global__ __launch_bounds__(576) void dh_kernel(
    const unsigned short* __restrict__ proj, const float* __restrict__ cw,
    unsigned short* __restrict__ loc_t, unsigned short* __restrict__ acc_t) {
  __shared__ f32x4 agf[6][96];
  __shared__ f32x4 agb[6][96];   // 18432 B
  const int tid = threadIdx.x;
  const int c4 = tid % 96;
  const int seg = tid / 96;      // wseg 0..5
  const int w0 = seg * 16;
  const int bid = blockIdx.x;
  const int bh = (bid & 7) * NH + (bid >> 3);   // XCD-chunked (768 = 8*96)
  const int h = bh % NH;
  const int b = bh / NH;

  f32x4 raw[9];
  const float* cwp = cw + (size_t)c4 * 36;
#pragma unroll
  for (int i = 0; i < 9; ++i) raw[i] = ldf4(cwp + i * 4);
  f32x4 qq[9];
#pragma unroll
  for (int tap = 0; tap < 9; ++tap)
#pragma unroll
    for (int c = 0; c < 4; ++c)
      qq[tap][c] = raw[(c * 9 + tap) >> 2][(c * 9 + tap) & 3];

  const bool hm = (h > 0), hp = (h < NH - 1);
  const unsigned short* rowm = proj + ((size_t)(bh - 1) * NW) * NC + c4 * 4;
  const unsigned short* rowc = proj + ((size_t)bh * NW) * NC + c4 * 4;
  const unsigned short* rowp = proj + ((size_t)(bh + 1) * NW) * NC + c4 * 4;
  unsigned short* tbase = loc_t + ((size_t)(b * NW + w0) * NH + h) * NC + c4 * 4;
  unsigned short* abase = acc_t + ((size_t)(b * NW + w0) * NH + h) * NC + c4 * 4;
  const size_t wst = (size_t)NH * NC;

  const f32x4 z = {0.f, 0.f, 0.f, 0.f};
  f32x4 colL[3], colC[3], colR[3];
  if (w0 > 0) {
    colL[0] = hm ? ldb4(rowm + (size_t)(w0 - 1) * NC) : z;
    colL[1] = ldb4(rowc + (size_t)(w0 - 1) * NC);
    colL[2] = hp ? ldb4(rowp + (size_t)(w0 - 1) * NC) : z;
  } else { colL[0] = z; colL[1] = z; colL[2] = z; }
  colC[0] = hm ? ldb4(rowm + (size_t)w0 * NC) : z;
  colC[1] = ldb4(rowc + (size_t)w0 * NC);
  colC[2] = hp ? ldb4(rowp + (size_t)w0 * NC) : z;

  uint2 xr[16];
#pragma unroll
  for (int i = 0; i < 16; ++i) {
    const int w = w0 + i;
    if (w + 1 < NW) {
      colR[0] = hm ? ldb4(rowm + (size_t)(w + 1) * NC) : z;
      colR[1] = ldb4(rowc + (size_t)(w + 1) * NC);
      colR[2] = hp ? ldb4(rowp + (size_t)(w + 1) * NC) : z;
    } else { colR[0] = z; colR[1] = z; colR[2] = z; }
    f32x4 a = colL[0] * qq[0] + colC[0] * qq[1] + colR[0] * qq[2]
            + colL[1] * qq[3] + colC[1] * qq[4] + colR[1] * qq[5]
            + colL[2] * qq[6] + colC[2] * qq[7] + colR[2] * qq[8];
    xr[i] = pk4(a);
    *reinterpret_cast<uint2*>(tbase + (size_t)i * wst) = xr[i];
    colL[0] = colC[0]; colL[1] = colC[1]; colL[2] = colC[2];
    colC[0] = colR[0]; colC[1] = colR[1]; colC[2] = colR[2];
  }

  f32x4 Af = z, Ab = z;
#pragma unroll
  for (int i = 0; i < 16; ++i) Af = DECAY * Af + GAIN * up4(xr[i]);
#pragma unroll
  for (int i = 15; i >= 0; --i) Ab = DECAY * Ab + GAIN * up4(xr[i]);
  agf[seg][c4] = Af; agb[seg][c4] = Ab;
  __syncthreads();
  f32x4 Fin = z, Bin = z;
  if (seg >= 1) Fin = agf[seg - 1][c4];
  if (seg >= 2) Fin += D16 * agf[seg - 2][c4];
  if (seg <= 4) Bin = agb[seg + 1][c4];
  if (seg <= 3) Bin += D16 * agb[seg + 2][c4];

  uint2 bwp[16];
  f32x4 Bs = Bin;
#pragma unroll
  for (int i = 15; i >= 0; --i) {
    Bs = DECAY * Bs + GAIN * up4(xr[i]);
    bwp[i] = pk4(Bs);
  }
  f32x4 Fs = Fin;
#pragma unroll
  for (int i = 0; i < 16; ++i) {
    Fs = DECAY * Fs + GAIN * up4(xr[i]);
    stb4(abase + (size_t)i * wst, Fs + up4(bwp[i]));
  }
}

// -- MEGA-FUSED: vertical scans + mix + layernorm + out_proj GEMM ------------
// block = (b,w), 768 threads = 12 waves, 1 block/CU (mix tile 73.7 KB).
// Scan: R12's exact form (VGPR 76, no spill). GEMM: BK=64 double-buffered
// (6 barriers, 12 MFMA/wave between barriers). Verified best: 174.7 us.
__global__ __launch_bounds__(768) void vgemm_kernel(
    const unsigned short* __restrict__ loc_t, const unsigned short* __restrict__ acc_t,
    const float* __restrict__ g, const float* __restrict__ bb,
    const unsigned short* __restrict__ WtO, const float* __restrict__ bo,
    float* __restrict__ out) {
  __shared__ __align__(16) unsigned short mix[96 * NC];   // 73728 B
  __shared__ __align__(16) unsigned short lsB[2][12288];  // 2 x 24576 B
  f32x4* ag = (f32x4*)mix;            // [2][8][96] multiplexed head (24.6 KB)
  char* mixc = (char*)mix;
  const int tid = threadIdx.x;
  const int lane = tid & 63;
  const int kg = lane >> 4, r16 = lane & 15;
  const int c4 = tid % 96;
  const int seg = tid / 96;                               // hseg 0..7
  const int h0 = seg * 12;
  const int bw = blockIdx.x;                              // b*NW + w

  // ---- prefetch B chunk 0 (64 k) async; drained by the phase-1 barrier ----
  {
    int d = tid % 192, kgg = tid / 192;                   // kgg 0..3
    gload16(WtO + (size_t)d * NC + kgg * 8, &lsB[0][tid * 8]);
    int s2 = tid + 768, d2 = s2 % 192, kg2 = s2 / 192;    // kg2 4..7
    gload16(WtO + (size_t)d2 * NC + kg2 * 8, &lsB[0][s2 * 8]);
  }

  // ---- phase 1: vertical scans (aggregate exchange, 12-row segments) ----
  const size_t base = ((size_t)bw * NH + h0) * NC + c4 * 4;
  const unsigned short* lp = loc_t + base;
  const unsigned short* ap = acc_t + base;
  uint2 xr[12], avp[12];
#pragma unroll
  for (int i = 0; i < 12; ++i) xr[i] = *reinterpret_cast<const uint2*>(lp + (size_t)i * NC);
#pragma unroll
  for (int i = 0; i < 12; ++i) avp[i] = *reinterpret_cast<const uint2*>(ap + (size_t)i * NC);

  const f32x4 z = {0.f, 0.f, 0.f, 0.f};
  f32x4 Af = z, Ab = z;
#pragma unroll
  for (int i = 0; i < 12; ++i) Af = DECAY * Af + GAIN * up4(xr[i]);
#pragma unroll
  for (int i = 11; i >= 0; --i) Ab = DECAY * Ab + GAIN * up4(xr[i]);
  ag[seg * 96 + c4] = Af;
  ag[768 + seg * 96 + c4] = Ab;
  __syncthreads();
  f32x4 Fin = z, Bin = z;
  if (seg >= 1) Fin = ag[(seg - 1) * 96 + c4];
  if (seg >= 2) Fin += D12 * ag[(seg - 2) * 96 + c4];
  if (seg >= 3) Fin += D24 * ag[(seg - 3) * 96 + c4];
  if (seg <= 6) Bin = ag[768 + (seg + 1) * 96 + c4];
  if (seg <= 5) Bin += D12 * ag[768 + (seg + 2) * 96 + c4];
  if (seg <= 4) Bin += D24 * ag[768 + (seg + 3) * 96 + c4];
  __syncthreads();                       // aggregate area free; mix writable

  // bwd pass: partial = x + 0.25*(acc + bt) -> swizzled mix tile
  f32x4 Bs = Bin;
#pragma unroll
  for (int i = 11; i >= 0; --i) {
    f32x4 xv = up4(xr[i]);
    Bs = DECAY * Bs + GAIN * xv;
    f32x4 part = xv + 0.25f * (up4(avp[i]) + Bs);
    stb4((unsigned short*)(mixc + mswz(h0 + i, c4 * 8)), part);
  }
  // fwd pass: final = partial + 0.25*tb (own slots)
  f32x4 Fs = Fin;
#pragma unroll
  for (int i = 0; i < 12; ++i) {
    Fs = DECAY * Fs + GAIN * up4(xr[i]);
    unsigned short* slot = (unsigned short*)(mixc + mswz(h0 + i, c4 * 8));
    stb4(slot, ldb4(slot) + 0.25f * Fs);
  }
  __syncthreads();

  // ---- phase 2: layernorm in-place in LDS (12 waves, wave-per-row) ----
  const int wave = tid >> 6;
  const int cb = lane * 6;
  {
    float gv[6], bv6[6];
#pragma unroll
    for (int i = 0; i < 6; ++i) { gv[i] = g[cb + i]; bv6[i] = bb[cb + i]; }
    for (int h = wave; h < NH; h += 12) {
      ushort2* p0 = (ushort2*)(mixc + mswz(h, lane * 12));
      ushort2* p1 = (ushort2*)(mixc + mswz(h, lane * 12 + 4));
      ushort2* p2 = (ushort2*)(mixc + mswz(h, lane * 12 + 8));
      ushort2 a2 = *p0, b2 = *p1, c2 = *p2;
      float v[6];
      v[0] = bf2f(a2.x); v[1] = bf2f(a2.y);
      v[2] = bf2f(b2.x); v[3] = bf2f(b2.y);
      v[4] = bf2f(c2.x); v[5] = bf2f(c2.y);
      float sm = 0.f, s2 = 0.f;
#pragma unroll
      for (int i = 0; i < 6; ++i) { sm += v[i]; s2 += v[i] * v[i]; }
#pragma unroll
      for (int o = 32; o > 0; o >>= 1) {
        sm += __shfl_xor(sm, o, 64);
        s2 += __shfl_xor(s2, o, 64);
      }
      float mu = sm * (1.f / NC);
      float r = rsqrtf(s2 * (1.f / NC) - mu * mu + 1e-5f);
      unsigned short o6[6];
#pragma unroll
      for (int i = 0; i < 6; ++i)
        o6[i] = f2bf((v[i] - mu) * r * gv[i] + bv6[i]);
      *p0 = (ushort2){o6[0], o6[1]};
      *p1 = (ushort2){o6[2], o6[3]};
      *p2 = (ushort2){o6[4], o6[5]};
    }
  }
  __syncthreads();

  // ---- phase 3: GEMM  out[96 x 192] = mix[96 x 384] @ WtO^T + b_out ----
  // BK=64 double-buffered: 6 chunks, 12 MFMA/wave between barriers.
  const int wm = wave >> 2, wn = wave & 3;     // 3x4 waves, 32x48 tiles
  f32x4 acc[2][3];
  {
    float bv[3];
#pragma unroll
    for (int n = 0; n < 3; ++n) bv[n] = bo[wn * 48 + n * 16 + r16];
#pragma unroll
    for (int m = 0; m < 2; ++m)
#pragma unroll
      for (int n = 0; n < 3; ++n)
        acc[m][n] = (f32x4){bv[n], bv[n], bv[n], bv[n]};
  }
  for (int ck = 0; ck < 6; ++ck) {
    if (ck < 5) {
      unsigned short* dst = lsB[(ck + 1) & 1];
      int d = tid % 192, kgg = tid / 192;
      gload16(WtO + (size_t)d * NC + (ck + 1) * 64 + kgg * 8, &dst[tid * 8]);
      int s2 = tid + 768, d2 = s2 % 192, kg2 = s2 / 192;
      gload16(WtO + (size_t)d2 * NC + (ck + 1) * 64 + kg2 * 8, &dst[s2 * 8]);
    }
    const unsigned short* bufp = lsB[ck & 1];
#pragma unroll
    for (int hh = 0; hh < 2; ++hh) {
      bf16x8 af[2], bfr[3];
#pragma unroll
      for (int m = 0; m < 2; ++m) {
        const int row = wm * 32 + m * 16 + r16;
        af[m] = *reinterpret_cast<const bf16x8*>(
            mixc + mswz(row, ck * 128 + hh * 64 + kg * 16));
      }
#pragma unroll
      for (int n = 0; n < 3; ++n)
        bfr[n] = *reinterpret_cast<const bf16x8*>(
            &bufp[((hh * 4 + kg) * 192 + wn * 48 + n * 16 + r16) * 8]);
#pragma unroll
      for (int m = 0; m < 2; ++m)
#pragma unroll
        for (int n = 0; n < 3; ++n)
          acc[m][n] = __builtin_amdgcn_mfma_f32_16x16x32_bf16(af[m], bfr[n], acc[m][n], 0, 0, 0);
    }
    __syncthreads();
  }

  // C write: rows are h of this (b,w) column -> out[(b,h,w)][d], f32
  const int bq = bw / NW, wq = bw % NW;
#pragma unroll
  for (int m = 0; m < 2; ++m) {
    const int hbase = wm * 32 + m * 16 + kg * 4;
#pragma unroll
    for (int n = 0; n < 3; ++n) {
      const int d = wn * 48 + n * 16 + r16;
#pragma unroll
      for (int j = 0; j < 4; ++j)
        out[((size_t)(bq * NH + hbase + j) * NW + wq) * ND + d] = acc[m][n][j];
    }
  }
}

extern "C" void kernel_launch(void* const* d_in, const int* in_sizes, int n_in,
                              void* d_out, int out_size, void* d_ws, size_t ws_size,
                              hipStream_t stream) {
  const float* x    = (const float*)d_in[0];
  const float* W_in = (const float*)d_in[1];
  const float* b_in = (const float*)d_in[2];
  const float* cw   = (const float*)d_in[3];
  const float* ln_g = (const float*)d_in[4];
  const float* ln_b = (const float*)d_in[5];
  const float* W_out= (const float*)d_in[6];
  const float* b_out= (const float*)d_in[7];
  float* out = (float*)d_out;

  // bf16 workspace layout (ushort element offsets); ~170 MB
  unsigned short* wsu   = (unsigned short*)d_ws;
  unsigned short* proj  = wsu;                          // 28,311,552 (b,h,w,c)
  unsigned short* loc_t = proj + 28311552;              // 28,311,552 (b,w,h,c)
  unsigned short* acc_t = loc_t + 28311552;             // 28,311,552 (b,w,h,c)
  unsigned short* WtI   = acc_t + 28311552;             // 73,728
  unsigned short* WtO   = WtI + 73728;                  // 73,728

  // 1) weight conversions (one launch)
  cvt_w_kernel<<<(2 * ND * NC) / 256, 256, 0, stream>>>(W_in, W_out, WtI, WtO);
  // 2) in_proj MFMA GEMM (reads f32 x directly) -> bf16 proj  [M,K=192,N=384]
  {
    dim3 g(NPOS / 128, NC / 128);
    gemm_kernel<ND, NC, 128><<<g, 256, 0, stream>>>(x, WtI, b_in, proj);
  }
  // 3) fused depthwise conv + horizontal scans -> loc_t, acc_t (transposed,
  //    XCD-chunked block map)
  dh_kernel<<<NB * NH, 576, 0, stream>>>(proj, cw, loc_t, acc_t);
  // 4) mega-fused vertical scans + mix + LN + out_proj GEMM -> f32 out
  vgemm_kernel<<<NB * NW, 768, 0, stream>>>(loc_t, acc_t, ln_g, ln_b,
                                            WtO, b_out, out);
}

// Round 22
// 171.680 us; speedup vs baseline: 1.0318x; 1.0187x over previous
//
#include <hip/hip_runtime.h>
#include <hip/hip_bf16.h>

// Problem constants (LegacyScan2DOperator): B=8, H=96, W=96, D=192, C=384.
#define NB 8
#define NH 96
#define NW 96
#define ND 192
#define NC 384
#define NPOS (NB*NH*NW)            // 73728 spatial positions

#define DECAY 0.6f
#define GAIN 0.4f
#define D12 2.1767823e-3f          // 0.6^12
#define D16 2.8211099e-4f          // 0.6^16
#define D24 4.7383813e-6f          // 0.6^24

typedef __attribute__((ext_vector_type(8))) short bf16x8;
typedef __attribute__((ext_vector_type(4))) float f32x4;
typedef __attribute__((ext_vector_type(4))) unsigned short us4;

__device__ inline unsigned short f2bf(float f) {
  unsigned u = __float_as_uint(f);
  u += 0x7fff + ((u >> 16) & 1);          // RNE
  return (unsigned short)(u >> 16);
}
__device__ inline float bf2f(unsigned short u) {
  return __uint_as_float((unsigned)u << 16);
}

__device__ inline void gload16(const void* g, void* l) {
  __builtin_amdgcn_global_load_lds(
      (const __attribute__((address_space(1))) void*)g,
      (__attribute__((address_space(3))) void*)l, 16, 0, 0);
}

__device__ inline f32x4 ldf4(const float* p) {
  return *reinterpret_cast<const f32x4*>(p);
}
__device__ inline f32x4 ldb4(const unsigned short* p) {
  us4 v = *reinterpret_cast<const us4*>(p);
  return (f32x4){bf2f(v.x), bf2f(v.y), bf2f(v.z), bf2f(v.w)};
}
__device__ inline void stb4(unsigned short* p, f32x4 v) {
  us4 o = {f2bf(v[0]), f2bf(v[1]), f2bf(v[2]), f2bf(v[3])};
  *reinterpret_cast<us4*>(p) = o;
}
// packed bf16x4 (uint2) <-> f32x4
__device__ inline uint2 pk4(f32x4 v) {
  us4 o = {f2bf(v[0]), f2bf(v[1]), f2bf(v[2]), f2bf(v[3])};
  uint2 r; __builtin_memcpy(&r, &o, 8); return r;
}
__device__ inline f32x4 up4(uint2 p) {
  return (f32x4){__uint_as_float(p.x << 16), __uint_as_float(p.x & 0xffff0000u),
                 __uint_as_float(p.y << 16), __uint_as_float(p.y & 0xffff0000u)};
}
// pack 8 f32 -> bf16x8
__device__ inline bf16x8 pk8(f32x4 a, f32x4 b) {
  bf16x8 r;
#pragma unroll
  for (int i = 0; i < 4; ++i) {
    r[i]     = (short)f2bf(a[i]);
    r[i + 4] = (short)f2bf(b[i]);
  }
  return r;
}
// swizzled byte offset inside the mix tile: row-major 768B rows, XOR bank fix
__device__ inline unsigned mswz(int row, int byteInRow) {
  return (unsigned)(row * 768 + (byteInRow ^ ((row & 7) << 4)));
}

// ------------- combined weight conversions (one launch) ---------------------
__global__ __launch_bounds__(256) void cvt_w_kernel(
    const float* __restrict__ Wi, const float* __restrict__ Wo,
    unsigned short* __restrict__ WtI, unsigned short* __restrict__ WtO) {
  int idx = blockIdx.x * 256 + threadIdx.x;
  if (idx < ND * NC) {
    int k = idx / NC, c = idx % NC;
    WtI[c * ND + k] = f2bf(Wi[idx]);
  } else {
    int j = idx - ND * NC;
    int k = j / ND, d = j % ND;
    WtO[d * NC + k] = f2bf(Wo[j]);
  }
}

// ---------------- MFMA GEMM (in_proj): proj = x @ W_in + b ------------------
// BM=256 x BN=128, 512 threads (8 waves as 4x2), wave tile 64x64.
// A is f32 in global, staged raw via global_load_lds with granule-XOR swizzle.
template<int K, int N>
__global__ __launch_bounds__(512) void gemm_kernel(
    const float* __restrict__ A32,
    const unsigned short* __restrict__ Bt,
    const float* __restrict__ bias,
    unsigned short* __restrict__ C) {
  __shared__ __align__(16) unsigned short lsA[16384];   // 256 x 32 f32 = 32 KB
  __shared__ __align__(16) unsigned short lsB[4096];    // 128 x 32 bf16 = 8 KB

  const int tid = threadIdx.x;
  const int lane = tid & 63;
  const int wid = tid >> 6;
  const int wm = wid >> 1, wn = wid & 1;     // 4 x 2 waves
  const int kg = lane >> 4, r16 = lane & 15;
  const int m0 = blockIdx.x * 256;
  const int n0 = blockIdx.y * 128;

  const float* srcAf[4]; float* dstAf[4];
  {
    float* lsAf = (float*)lsA;
#pragma unroll
    for (int p = 0; p < 4; ++p) {
      int s = tid + p * 512;              // 2048 slots of 16B
      int row = s >> 3, g = s & 7;
      int gg = g ^ (row & 7);
      srcAf[p] = A32 + (size_t)(m0 + row) * K + gg * 4;
      dstAf[p] = lsAf + s * 4;
    }
  }
  const unsigned short* srcB0 = Bt + (size_t)(n0 + (tid & 127)) * K + (tid >> 7) * 8;

  int boff[4];
#pragma unroll
  for (int n = 0; n < 4; ++n)
    boff[n] = (kg * 128 + wn * 64 + n * 16 + r16) * 8;

  f32x4 acc[4][4];
  {
    float bv[4];
#pragma unroll
    for (int n = 0; n < 4; ++n) bv[n] = bias[n0 + wn * 64 + n * 16 + r16];
#pragma unroll
    for (int m = 0; m < 4; ++m)
#pragma unroll
      for (int n = 0; n < 4; ++n)
        acc[m][n] = (f32x4){bv[n], bv[n], bv[n], bv[n]};
  }

  for (int ks = 0; ks < K / 32; ++ks) {
    const int ke = ks * 32;
#pragma unroll
    for (int p = 0; p < 4; ++p) gload16(srcAf[p] + ke, dstAf[p]);
    gload16(srcB0 + ke, &lsB[tid * 8]);
    __syncthreads();
    bf16x8 af[4], bfr[4];
    {
      const float* lsAf = (const float*)lsA;
      const int r7 = r16 & 7;
#pragma unroll
      for (int m = 0; m < 4; ++m) {
        const int rowf = wm * 64 + m * 16 + r16;
        const float* rp = lsAf + rowf * 32;
        f32x4 a0 = *reinterpret_cast<const f32x4*>(rp + ((2 * kg) ^ r7) * 4);
        f32x4 a1 = *reinterpret_cast<const f32x4*>(rp + ((2 * kg + 1) ^ r7) * 4);
        af[m] = pk8(a0, a1);
      }
    }
#pragma unroll
    for (int n = 0; n < 4; ++n)
      bfr[n] = *reinterpret_cast<const bf16x8*>(&lsB[boff[n]]);
#pragma unroll
    for (int m = 0; m < 4; ++m)
#pragma unroll
      for (int n = 0; n < 4; ++n)
        acc[m][n] = __builtin_amdgcn_mfma_f32_16x16x32_bf16(af[m], bfr[n], acc[m][n], 0, 0, 0);
    __syncthreads();
  }

#pragma unroll
  for (int m = 0; m < 4; ++m) {
    const int row = m0 + wm * 64 + m * 16 + kg * 4;
#pragma unroll
    for (int n = 0; n < 4; ++n) {
      const int col = n0 + wn * 64 + n * 16 + r16;
#pragma unroll
      for (int j = 0; j < 4; ++j)
        C[(size_t)(row + j) * N + col] = f2bf(acc[m][n][j]);
    }
  }
}

// -- fused depthwise 3x3 conv + horizontal scans (aggregate exchange) --------
// block -> (b,h) via XCD-chunked map: all h of one batch image on one XCD,
// so the bh-1/bh+1 proj rows are L2-resident. 576 thr = (c4, wseg of 16).
// Writes loc_t / acc_t (b,w,h,c) transposed, SEPARATE buffers (interleaving
// regressed 2.5x — R11; 256B stride padding was null — R19).
__global__ __launch_bounds__(576) void dh_kernel(
    const unsigned short* __restrict__ proj, const float* __restrict__ cw,
    unsigned short* __restrict__ loc_t, unsigned short* __restrict__ acc_t) {
  __shared__ f32x4 agf[6][96];
  __shared__ f32x4 agb[6][96];   // 18432 B
  const int tid = threadIdx.x;
  const int c4 = tid % 96;
  const int seg = tid / 96;      // wseg 0..5
  const int w0 = seg * 16;
  const int bid = blockIdx.x;
  const int bh = (bid & 7) * NH + (bid >> 3);   // XCD-chunked (768 = 8*96)
  const int h = bh % NH;
  const int b = bh / NH;

  f32x4 raw[9];
  const float* cwp = cw + (size_t)c4 * 36;
#pragma unroll
  for (int i = 0; i < 9; ++i) raw[i] = ldf4(cwp + i * 4);
  f32x4 qq[9];
#pragma unroll
  for (int tap = 0; tap < 9; ++tap)
#pragma unroll
    for (int c = 0; c < 4; ++c)
      qq[tap][c] = raw[(c * 9 + tap) >> 2][(c * 9 + tap) & 3];

  const bool hm = (h > 0), hp = (h < NH - 1);
  const unsigned short* rowm = proj + ((size_t)(bh - 1) * NW) * NC + c4 * 4;
  const unsigned short* rowc = proj + ((size_t)bh * NW) * NC + c4 * 4;
  const unsigned short* rowp = proj + ((size_t)(bh + 1) * NW) * NC + c4 * 4;
  unsigned short* tbase = loc_t + ((size_t)(b * NW + w0) * NH + h) * NC + c4 * 4;
  unsigned short* abase = acc_t + ((size_t)(b * NW + w0) * NH + h) * NC + c4 * 4;
  const size_t wst = (size_t)NH * NC;

  const f32x4 z = {0.f, 0.f, 0.f, 0.f};
  f32x4 colL[3], colC[3], colR[3];
  if (w0 > 0) {
    colL[0] = hm ? ldb4(rowm + (size_t)(w0 - 1) * NC) : z;
    colL[1] = ldb4(rowc + (size_t)(w0 - 1) * NC);
    colL[2] = hp ? ldb4(rowp + (size_t)(w0 - 1) * NC) : z;
  } else { colL[0] = z; colL[1] = z; colL[2] = z; }
  colC[0] = hm ? ldb4(rowm + (size_t)w0 * NC) : z;
  colC[1] = ldb4(rowc + (size_t)w0 * NC);
  colC[2] = hp ? ldb4(rowp + (size_t)w0 * NC) : z;

  uint2 xr[16];
#pragma unroll
  for (int i = 0; i < 16; ++i) {
    const int w = w0 + i;
    if (w + 1 < NW) {
      colR[0] = hm ? ldb4(rowm + (size_t)(w + 1) * NC) : z;
      colR[1] = ldb4(rowc + (size_t)(w + 1) * NC);
      colR[2] = hp ? ldb4(rowp + (size_t)(w + 1) * NC) : z;
    } else { colR[0] = z; colR[1] = z; colR[2] = z; }
    f32x4 a = colL[0] * qq[0] + colC[0] * qq[1] + colR[0] * qq[2]
            + colL[1] * qq[3] + colC[1] * qq[4] + colR[1] * qq[5]
            + colL[2] * qq[6] + colC[2] * qq[7] + colR[2] * qq[8];
    xr[i] = pk4(a);
    *reinterpret_cast<uint2*>(tbase + (size_t)i * wst) = xr[i];
    colL[0] = colC[0]; colL[1] = colC[1]; colL[2] = colC[2];
    colC[0] = colR[0]; colC[1] = colR[1]; colC[2] = colR[2];
  }

  f32x4 Af = z, Ab = z;
#pragma unroll
  for (int i = 0; i < 16; ++i) Af = DECAY * Af + GAIN * up4(xr[i]);
#pragma unroll
  for (int i = 15; i >= 0; --i) Ab = DECAY * Ab + GAIN * up4(xr[i]);
  agf[seg][c4] = Af; agb[seg][c4] = Ab;
  __syncthreads();
  f32x4 Fin = z, Bin = z;
  if (seg >= 1) Fin = agf[seg - 1][c4];
  if (seg >= 2) Fin += D16 * agf[seg - 2][c4];
  if (seg <= 4) Bin = agb[seg + 1][c4];
  if (seg <= 3) Bin += D16 * agb[seg + 2][c4];

  uint2 bwp[16];
  f32x4 Bs = Bin;
#pragma unroll
  for (int i = 15; i >= 0; --i) {
    Bs = DECAY * Bs + GAIN * up4(xr[i]);
    bwp[i] = pk4(Bs);
  }
  f32x4 Fs = Fin;
#pragma unroll
  for (int i = 0; i < 16; ++i) {
    Fs = DECAY * Fs + GAIN * up4(xr[i]);
    stb4(abase + (size_t)i * wst, Fs + up4(bwp[i]));
  }
}

// -- MEGA-FUSED: vertical scans + mix + layernorm + out_proj GEMM ------------
// block = (b,w), 768 threads = 12 waves, 1 block/CU (mix tile 73.7 KB).
// Scan: R12's exact form (VGPR 76, no spill). GEMM: BK=64 double-buffered
// (6 barriers, 12 MFMA/wave between barriers). Verified best: 174.7 us.
__global__ __launch_bounds__(768) void vgemm_kernel(
    const unsigned short* __restrict__ loc_t, const unsigned short* __restrict__ acc_t,
    const float* __restrict__ g, const float* __restrict__ bb,
    const unsigned short* __restrict__ WtO, const float* __restrict__ bo,
    float* __restrict__ out) {
  __shared__ __align__(16) unsigned short mix[96 * NC];   // 73728 B
  __shared__ __align__(16) unsigned short lsB[2][12288];  // 2 x 24576 B
  f32x4* ag = (f32x4*)mix;            // [2][8][96] multiplexed head (24.6 KB)
  char* mixc = (char*)mix;
  const int tid = threadIdx.x;
  const int lane = tid & 63;
  const int kg = lane >> 4, r16 = lane & 15;
  const int c4 = tid % 96;
  const int seg = tid / 96;                               // hseg 0..7
  const int h0 = seg * 12;
  const int bw = blockIdx.x;                              // b*NW + w

  // ---- prefetch B chunk 0 (64 k) async; drained by the phase-1 barrier ----
  {
    int d = tid % 192, kgg = tid / 192;                   // kgg 0..3
    gload16(WtO + (size_t)d * NC + kgg * 8, &lsB[0][tid * 8]);
    int s2 = tid + 768, d2 = s2 % 192, kg2 = s2 / 192;    // kg2 4..7
    gload16(WtO + (size_t)d2 * NC + kg2 * 8, &lsB[0][s2 * 8]);
  }

  // ---- phase 1: vertical scans (aggregate exchange, 12-row segments) ----
  const size_t base = ((size_t)bw * NH + h0) * NC + c4 * 4;
  const unsigned short* lp = loc_t + base;
  const unsigned short* ap = acc_t + base;
  uint2 xr[12], avp[12];
#pragma unroll
  for (int i = 0; i < 12; ++i) xr[i] = *reinterpret_cast<const uint2*>(lp + (size_t)i * NC);
#pragma unroll
  for (int i = 0; i < 12; ++i) avp[i] = *reinterpret_cast<const uint2*>(ap + (size_t)i * NC);

  const f32x4 z = {0.f, 0.f, 0.f, 0.f};
  f32x4 Af = z, Ab = z;
#pragma unroll
  for (int i = 0; i < 12; ++i) Af = DECAY * Af + GAIN * up4(xr[i]);
#pragma unroll
  for (int i = 11; i >= 0; --i) Ab = DECAY * Ab + GAIN * up4(xr[i]);
  ag[seg * 96 + c4] = Af;
  ag[768 + seg * 96 + c4] = Ab;
  __syncthreads();
  f32x4 Fin = z, Bin = z;
  if (seg >= 1) Fin = ag[(seg - 1) * 96 + c4];
  if (seg >= 2) Fin += D12 * ag[(seg - 2) * 96 + c4];
  if (seg >= 3) Fin += D24 * ag[(seg - 3) * 96 + c4];
  if (seg <= 6) Bin = ag[768 + (seg + 1) * 96 + c4];
  if (seg <= 5) Bin += D12 * ag[768 + (seg + 2) * 96 + c4];
  if (seg <= 4) Bin += D24 * ag[768 + (seg + 3) * 96 + c4];
  __syncthreads();                       // aggregate area free; mix writable

  // bwd pass: partial = x + 0.25*(acc + bt) -> swizzled mix tile
  f32x4 Bs = Bin;
#pragma unroll
  for (int i = 11; i >= 0; --i) {
    f32x4 xv = up4(xr[i]);
    Bs = DECAY * Bs + GAIN * xv;
    f32x4 part = xv + 0.25f * (up4(avp[i]) + Bs);
    stb4((unsigned short*)(mixc + mswz(h0 + i, c4 * 8)), part);
  }
  // fwd pass: final = partial + 0.25*tb (own slots)
  f32x4 Fs = Fin;
#pragma unroll
  for (int i = 0; i < 12; ++i) {
    Fs = DECAY * Fs + GAIN * up4(xr[i]);
    unsigned short* slot = (unsigned short*)(mixc + mswz(h0 + i, c4 * 8));
    stb4(slot, ldb4(slot) + 0.25f * Fs);
  }
  __syncthreads();

  // ---- phase 2: layernorm in-place in LDS (12 waves, wave-per-row) ----
  const int wave = tid >> 6;
  const int cb = lane * 6;
  {
    float gv[6], bv6[6];
#pragma unroll
    for (int i = 0; i < 6; ++i) { gv[i] = g[cb + i]; bv6[i] = bb[cb + i]; }
    for (int h = wave; h < NH; h += 12) {
      ushort2* p0 = (ushort2*)(mixc + mswz(h, lane * 12));
      ushort2* p1 = (ushort2*)(mixc + mswz(h, lane * 12 + 4));
      ushort2* p2 = (ushort2*)(mixc + mswz(h, lane * 12 + 8));
      ushort2 a2 = *p0, b2 = *p1, c2 = *p2;
      float v[6];
      v[0] = bf2f(a2.x); v[1] = bf2f(a2.y);
      v[2] = bf2f(b2.x); v[3] = bf2f(b2.y);
      v[4] = bf2f(c2.x); v[5] = bf2f(c2.y);
      float sm = 0.f, s2 = 0.f;
#pragma unroll
      for (int i = 0; i < 6; ++i) { sm += v[i]; s2 += v[i] * v[i]; }
#pragma unroll
      for (int o = 32; o > 0; o >>= 1) {
        sm += __shfl_xor(sm, o, 64);
        s2 += __shfl_xor(s2, o, 64);
      }
      float mu = sm * (1.f / NC);
      float r = rsqrtf(s2 * (1.f / NC) - mu * mu + 1e-5f);
      unsigned short o6[6];
#pragma unroll
      for (int i = 0; i < 6; ++i)
        o6[i] = f2bf((v[i] - mu) * r * gv[i] + bv6[i]);
      *p0 = (ushort2){o6[0], o6[1]};
      *p1 = (ushort2){o6[2], o6[3]};
      *p2 = (ushort2){o6[4], o6[5]};
    }
  }
  __syncthreads();

  // ---- phase 3: GEMM  out[96 x 192] = mix[96 x 384] @ WtO^T + b_out ----
  // BK=64 double-buffered: 6 chunks, 12 MFMA/wave between barriers.
  const int wm = wave >> 2, wn = wave & 3;     // 3x4 waves, 32x48 tiles
  f32x4 acc[2][3];
  {
    float bv[3];
#pragma unroll
    for (int n = 0; n < 3; ++n) bv[n] = bo[wn * 48 + n * 16 + r16];
#pragma unroll
    for (int m = 0; m < 2; ++m)
#pragma unroll
      for (int n = 0; n < 3; ++n)
        acc[m][n] = (f32x4){bv[n], bv[n], bv[n], bv[n]};
  }
  for (int ck = 0; ck < 6; ++ck) {
    if (ck < 5) {
      unsigned short* dst = lsB[(ck + 1) & 1];
      int d = tid % 192, kgg = tid / 192;
      gload16(WtO + (size_t)d * NC + (ck + 1) * 64 + kgg * 8, &dst[tid * 8]);
      int s2 = tid + 768, d2 = s2 % 192, kg2 = s2 / 192;
      gload16(WtO + (size_t)d2 * NC + (ck + 1) * 64 + kg2 * 8, &dst[s2 * 8]);
    }
    const unsigned short* bufp = lsB[ck & 1];
#pragma unroll
    for (int hh = 0; hh < 2; ++hh) {
      bf16x8 af[2], bfr[3];
#pragma unroll
      for (int m = 0; m < 2; ++m) {
        const int row = wm * 32 + m * 16 + r16;
        af[m] = *reinterpret_cast<const bf16x8*>(
            mixc + mswz(row, ck * 128 + hh * 64 + kg * 16));
      }
#pragma unroll
      for (int n = 0; n < 3; ++n)
        bfr[n] = *reinterpret_cast<const bf16x8*>(
            &bufp[((hh * 4 + kg) * 192 + wn * 48 + n * 16 + r16) * 8]);
#pragma unroll
      for (int m = 0; m < 2; ++m)
#pragma unroll
        for (int n = 0; n < 3; ++n)
          acc[m][n] = __builtin_amdgcn_mfma_f32_16x16x32_bf16(af[m], bfr[n], acc[m][n], 0, 0, 0);
    }
    __syncthreads();
  }

  // C write: rows are h of this (b,w) column -> out[(b,h,w)][d], f32
  const int bq = bw / NW, wq = bw % NW;
#pragma unroll
  for (int m = 0; m < 2; ++m) {
    const int hbase = wm * 32 + m * 16 + kg * 4;
#pragma unroll
    for (int n = 0; n < 3; ++n) {
      const int d = wn * 48 + n * 16 + r16;
#pragma unroll
      for (int j = 0; j < 4; ++j)
        out[((size_t)(bq * NH + hbase + j) * NW + wq) * ND + d] = acc[m][n][j];
    }
  }
}

extern "C" void kernel_launch(void* const* d_in, const int* in_sizes, int n_in,
                              void* d_out, int out_size, void* d_ws, size_t ws_size,
                              hipStream_t stream) {
  const float* x    = (const float*)d_in[0];
  const float* W_in = (const float*)d_in[1];
  const float* b_in = (const float*)d_in[2];
  const float* cw   = (const float*)d_in[3];
  const float* ln_g = (const float*)d_in[4];
  const float* ln_b = (const float*)d_in[5];
  const float* W_out= (const float*)d_in[6];
  const float* b_out= (const float*)d_in[7];
  float* out = (float*)d_out;

  // bf16 workspace layout (ushort element offsets); ~170 MB
  unsigned short* wsu   = (unsigned short*)d_ws;
  unsigned short* proj  = wsu;                          // 28,311,552 (b,h,w,c)
  unsigned short* loc_t = proj + 28311552;              // 28,311,552 (b,w,h,c)
  unsigned short* acc_t = loc_t + 28311552;             // 28,311,552 (b,w,h,c)
  unsigned short* WtI   = acc_t + 28311552;             // 73,728
  unsigned short* WtO   = WtI + 73728;                  // 73,728

  // 1) weight conversions (one launch)
  cvt_w_kernel<<<(2 * ND * NC) / 256, 256, 0, stream>>>(W_in, W_out, WtI, WtO);
  // 2) in_proj MFMA GEMM (reads f32 x directly) -> bf16 proj  [M,K=192,N=384]
  //    BM=256 x BN=128, 512 threads
  {
    dim3 g(NPOS / 256, NC / 128);
    gemm_kernel<ND, NC><<<g, 512, 0, stream>>>(x, WtI, b_in, proj);
  }
  // 3) fused depthwise conv + horizontal scans -> loc_t, acc_t (transposed,
  //    XCD-chunked block map)
  dh_kernel<<<NB * NH, 576, 0, stream>>>(proj, cw, loc_t, acc_t);
  // 4) mega-fused vertical scans + mix + LN + out_proj GEMM -> f32 out
  vgemm_kernel<<<NB * NW, 768, 0, stream>>>(loc_t, acc_t, ln_g, ln_b,
                                            WtO, b_out, out);
}